// Round 6
// baseline (689.590 us; speedup 1.0000x reference)
//
#include <hip/hip_runtime.h>

#define NN 65536
#define BB 64
#define HH 1024
#define MM 64
#define RR 4

__device__ __forceinline__ float waveReduceSum(float v) {
#pragma unroll
  for (int off = 32; off > 0; off >>= 1) v += __shfl_xor(v, off, 64);
  return v;
}

// fast pow for positive base: wt^p = exp(p * log(wt))
__device__ __forceinline__ float fastPow(float wt, float p) {
  return __expf(p * __logf(wt));
}

// shifted, gated interpolation weight at n (lane == n % 64).
// wg(x) = gb*E[x]*rinv + (1-gb)*w[x]; returns s0*wg(n-1)+s1*wg(n)+s2*wg(n+1)
__device__ __forceinline__ float shifted_wg(
    const float* __restrict__ Eb, const float* __restrict__ wb, int n,
    float gb, float rinv, float s0, float s1, float s2) {
  const int lane = threadIdx.x & 63;
  const float omg = 1.f - gb;
  const float wgc = gb * Eb[n] * rinv + omg * wb[n];
  float wgm = __shfl_up(wgc, 1, 64);
  float wgp = __shfl_down(wgc, 1, 64);
  if (lane == 0)  wgm = (n > 0)      ? (gb * Eb[n - 1] * rinv + omg * wb[n - 1]) : 0.f;
  if (lane == 63) wgp = (n < NN - 1) ? (gb * Eb[n + 1] * rinv + omg * wb[n + 1]) : 0.f;
  return s0 * wgm + s1 * wgc + s2 * wgp;
}

// ---------------------------------------------------------------------------
// K1: per-batch head parameters from h_t. grid 64, block 256.
// Also zero-inits acc_out (16384 = 64 blocks x 256) and RS/GS (block 0).
// ---------------------------------------------------------------------------
__global__ __launch_bounds__(256) void prep_kernel(
    const float* __restrict__ h_t,
    const float* __restrict__ key_w, const float* __restrict__ key_b,
    const float* __restrict__ beta_w, const float* __restrict__ beta_b,
    const float* __restrict__ gate_w, const float* __restrict__ gate_b,
    const float* __restrict__ shift_w, const float* __restrict__ shift_b,
    const float* __restrict__ gamma_w, const float* __restrict__ gamma_b,
    const float* __restrict__ erase_w, const float* __restrict__ erase_b,
    const float* __restrict__ add_w, const float* __restrict__ add_b,
    float* __restrict__ kn, float* __restrict__ e_v, float* __restrict__ a_v,
    float* __restrict__ beta, float* __restrict__ g, float* __restrict__ gamma_,
    float* __restrict__ s,
    float* __restrict__ RS0, float* __restrict__ RS1, float* __restrict__ GS,
    float* __restrict__ acc_out)
{
  const int b = blockIdx.x;
  const int t = threadIdx.x;
  __shared__ float h_sh[HH];
  __shared__ float part3[3][64][5];
  __shared__ float k_sh[64];
  acc_out[b * 256 + t] = 0.f;
#pragma unroll
  for (int i = 0; i < 4; i++) h_sh[t + 256 * i] = h_t[b * HH + t + 256 * i];
  __syncthreads();

  const int c = t & 63, grp = t >> 6;
  const int h0 = grp * 256;
  float dk = 0.f, de = 0.f, da = 0.f;
#pragma unroll 4
  for (int i = 0; i < 256; i++) {
    const float hv = h_sh[h0 + i];
    dk += hv * key_w[(h0 + i) * 64 + c];
    de += hv * erase_w[(h0 + i) * 64 + c];
    da += hv * add_w[(h0 + i) * 64 + c];
  }
  part3[0][c][grp] = dk;
  part3[1][c][grp] = de;
  part3[2][c][grp] = da;
  __syncthreads();

  if (t < 64) {
    const float v = part3[0][t][0] + part3[0][t][1] + part3[0][t][2] + part3[0][t][3];
    k_sh[t] = fminf(fmaxf(v + key_b[t], 0.f), 1.f);
  } else if (t < 128) {
    const int m = t - 64;
    const float v = part3[1][m][0] + part3[1][m][1] + part3[1][m][2] + part3[1][m][3];
    e_v[b * 64 + m] = fminf(fmaxf(v + erase_b[m], 0.f), 1.f);
  } else if (t < 192) {
    const int m = t - 128;
    const float v = part3[2][m][0] + part3[2][m][1] + part3[2][m][2] + part3[2][m][3];
    a_v[b * 64 + m] = fminf(fmaxf(v + add_b[m], 0.f), 1.f);  // relu+clip01 == clip01
  } else {
    const int lane = t - 192;
    float outs[6];
#pragma unroll 1
    for (int o = 0; o < 6; o++) {
      float d = 0.f;
      if (o < 3) {
        const float* W = (o == 0) ? beta_w : ((o == 1) ? gate_w : gamma_w);
        for (int hh = lane; hh < HH; hh += 64) d += h_sh[hh] * W[hh];
      } else {
        const int j = o - 3;
        for (int hh = lane; hh < HH; hh += 64) d += h_sh[hh] * shift_w[hh * 3 + j];
      }
      outs[o] = waveReduceSum(d);
    }
    if (lane == 0) {
      beta[b]   = fmaxf(outs[0] + beta_b[0], 0.f);
      g[b]      = fminf(fmaxf(outs[1] + gate_b[0], 0.f), 1.f);
      gamma_[b] = 1.0f + fmaxf(outs[2] + gamma_b[0], 0.f);
      const float l0 = outs[3] + shift_b[0];
      const float l1 = outs[4] + shift_b[1];
      const float l2 = outs[5] + shift_b[2];
      const float mx = fmaxf(l0, fmaxf(l1, l2));
      const float e0 = __expf(l0 - mx), e1 = __expf(l1 - mx), e2 = __expf(l2 - mx);
      const float inv = 1.f / (e0 + e1 + e2);
      s[b * 3 + 0] = e0 * inv; s[b * 3 + 1] = e1 * inv; s[b * 3 + 2] = e2 * inv;
    }
  }
  __syncthreads();
  if (t < 64) {
    float ss = 0.f;
    for (int j = 0; j < 64; j++) ss += k_sh[j] * k_sh[j];
    kn[b * 64 + t] = k_sh[t] / (sqrtf(ss) + 1e-8f);
  }
  if (b == 0) {
    if (t < 64) { RS0[t] = 0.f; RS1[t] = 0.f; }
    if (t < 5) GS[t] = 0.f;
  }
}

// ---------------------------------------------------------------------------
// K2 / K5: content addressing. grid (512 n-chunks of 128, 2 b-halves), 256 t.
// Rows in registers; kn/beta via wave-uniform scalar loads (readfirstlane).
// ---------------------------------------------------------------------------
__global__ __launch_bounds__(256) void content_kernel(
    const float* __restrict__ mem, const int* __restrict__ bank,
    const float* __restrict__ kn, const float* __restrict__ beta,
    float* __restrict__ E, float* __restrict__ RS)
{
  const float* Mrow = mem + (bank ? ((size_t)(*bank) * (size_t)NN * MM) : (size_t)0);
  const int t = threadIdx.x;
  const int nl = t & 127;
  const int n = blockIdx.x * 128 + nl;
  const int bgrp = t >> 7;                 // 0/1: which 16-b group
  const int nhalf = (t >> 6) & 1;          // which 64-n half
  const int lane = t & 63;
  const int b0 = blockIdx.y * 32 + bgrp * 16;

  float4 row[16];
  const float4* rp = (const float4*)(Mrow + (size_t)n * MM);
#pragma unroll
  for (int q = 0; q < 16; q++) row[q] = rp[q];
  float ss = 0.f;
#pragma unroll
  for (int q = 0; q < 16; q++)
    ss += row[q].x * row[q].x + row[q].y * row[q].y + row[q].z * row[q].z + row[q].w * row[q].w;
  const float rinv = 1.0f / (sqrtf(ss) + 1e-8f);

  __shared__ float accs[32][2];
  for (int i = 0; i < 16; i++) {
    const int rb = __builtin_amdgcn_readfirstlane(b0 + i);
    const float4* kp = (const float4*)(kn + rb * 64);
    float dot = 0.f;
#pragma unroll
    for (int q = 0; q < 16; q++) {
      const float4 kq = kp[q];
      dot += kq.x * row[q].x + kq.y * row[q].y + kq.z * row[q].z + kq.w * row[q].w;
    }
    const float e = __expf(beta[rb] * dot * rinv);
    E[(size_t)rb * NN + n] = e;
    const float r = waveReduceSum(e);
    if (lane == 0) accs[bgrp * 16 + i][nhalf] = r;
  }
  __syncthreads();
  if (t < 32) atomicAdd(&RS[blockIdx.y * 32 + t], accs[t][0] + accs[t][1]);
}

// ---------------------------------------------------------------------------
// K3 (both heads): streaming w_pow producer. grid (64 n-chunks of 1024, 64 b),
// block 256. W[b][n] = w_pow (unnormalized); GSslot += sum. No barriers in
// the hot path, ~full occupancy, pure coalesced streaming.
// ---------------------------------------------------------------------------
__global__ __launch_bounds__(256) void wpow_kernel(
    const float* __restrict__ E, const float* __restrict__ wprev,
    const float* __restrict__ RS, const float* __restrict__ g,
    const float* __restrict__ gamma_, const float* __restrict__ s,
    float* __restrict__ W, float* __restrict__ GSslot)
{
  const int b = blockIdx.y;
  const float gb = g[b], gmb = gamma_[b];
  const float s0 = s[b * 3], s1 = s[b * 3 + 1], s2 = s[b * 3 + 2];
  const float rinv = 1.0f / RS[b];
  const float* Eb = E + (size_t)b * NN;
  const float* wb = wprev + (size_t)b * NN;
  float* Wb = W + (size_t)b * NN;
  const int base = blockIdx.x * 1024;
  float acc = 0.f;
#pragma unroll
  for (int k = 0; k < 4; k++) {
    const int n = base + k * 256 + threadIdx.x;
    const float wt = shifted_wg(Eb, wb, n, gb, rinv, s0, s1, s2);
    const float wp = fastPow(wt, gmb);
    Wb[n] = wp;
    acc += wp;
  }
  __shared__ float wsum[4];
  const float w = waveReduceSum(acc);
  if ((threadIdx.x & 63) == 0) wsum[threadIdx.x >> 6] = w;
  __syncthreads();
  if (threadIdx.x == 0) atomicAdd(GSslot, wsum[0] + wsum[1] + wsum[2] + wsum[3]);
}

// ---------------------------------------------------------------------------
// K4: apply write head: m1 = m0*(1 - ww_new^T e) + ww_new^T a, with
// ww_new = W0 * invGS staged in LDS. grid 1024 (64-n), block 256.
// Phase-2 thread = (nl = t>>2, mq = t&3): er/ad[16] rank-64 update.
// ---------------------------------------------------------------------------
__global__ __launch_bounds__(256) void apply_write_kernel(
    const float* __restrict__ W0, const float* __restrict__ GS,
    const float* __restrict__ e_v, const float* __restrict__ a_v,
    const float* __restrict__ memory, const int* __restrict__ bank,
    float* __restrict__ m1)
{
  __shared__ float cw[64 * 66];
  __shared__ float e_sh[4096];
  __shared__ float a_sh[4096];
  const int t = threadIdx.x;
  const int n0 = blockIdx.x * 64;
  const float invGS = 1.0f / (GS[0] + 1e-5f);
#pragma unroll
  for (int q = 0; q < 4; q++) {
    ((float4*)e_sh)[t + 256 * q] = ((const float4*)e_v)[t + 256 * q];
    ((float4*)a_sh)[t + 256 * q] = ((const float4*)a_v)[t + 256 * q];
  }
#pragma unroll
  for (int rep = 0; rep < 16; rep++) {
    const int idx = rep * 256 + t;
    const int b = idx >> 6, nl = idx & 63;
    cw[b * 66 + nl] = W0[(size_t)b * NN + n0 + nl] * invGS;
  }
  __syncthreads();
  const int nl = t >> 2, mq = t & 3;
  const int n = n0 + nl;
  float er[16], ad[16];
#pragma unroll
  for (int j = 0; j < 16; j++) { er[j] = 0.f; ad[j] = 0.f; }
  for (int b = 0; b < 64; b++) {
    const float c = cw[b * 66 + nl];
#pragma unroll
    for (int j = 0; j < 4; j++) {
      const float4 ev = *((const float4*)&e_sh[b * 64 + mq * 16 + j * 4]);
      const float4 av = *((const float4*)&a_sh[b * 64 + mq * 16 + j * 4]);
      er[j * 4 + 0] += c * ev.x; er[j * 4 + 1] += c * ev.y;
      er[j * 4 + 2] += c * ev.z; er[j * 4 + 3] += c * ev.w;
      ad[j * 4 + 0] += c * av.x; ad[j * 4 + 1] += c * av.y;
      ad[j * 4 + 2] += c * av.z; ad[j * 4 + 3] += c * av.w;
    }
  }
  const float* M0 = memory + (size_t)(*bank) * (size_t)NN * MM;
  const float4* m0p = (const float4*)(M0 + (size_t)n * MM + mq * 16);
  float4* m1p = (float4*)(m1 + (size_t)n * MM + mq * 16);
#pragma unroll
  for (int j = 0; j < 4; j++) {
    const float4 mv = m0p[j];
    float4 o;
    o.x = mv.x * (1.f - er[j * 4 + 0]) + ad[j * 4 + 0];
    o.y = mv.y * (1.f - er[j * 4 + 1]) + ad[j * 4 + 1];
    o.z = mv.z * (1.f - er[j * 4 + 2]) + ad[j * 4 + 2];
    o.w = mv.w * (1.f - er[j * 4 + 3]) + ad[j * 4 + 3];
    m1p[j] = o;
  }
}

// ---------------------------------------------------------------------------
// K6 (per r): part[sc][b][m] = sum_{n in sc} W[b][n] * m1[n][m].
// grid 1024 (one 64-n tile per block), block 256. 34 KB LDS -> 4 blocks/CU.
// Proven R3 inner loop: acc = 4b x 4m register tile (16 VGPRs).
// ---------------------------------------------------------------------------
__global__ __launch_bounds__(256) void gemm_kernel(
    const float* __restrict__ W, const float* __restrict__ m1,
    float* __restrict__ part)
{
  const int sc = blockIdx.x;
  const int t = threadIdx.x;
  const int n0 = sc * 64;
  __shared__ float m1_sh[64 * 68];
  __shared__ float w_sh[64 * 66];
  // stage m1 tile [64n x 64m] (pad 68)
#pragma unroll
  for (int rep = 0; rep < 4; rep++) {
    const int nl2 = rep * 16 + (t >> 4);
    const int mc = t & 15;
    *((float4*)&m1_sh[nl2 * 68 + mc * 4]) =
        ((const float4*)(m1 + (size_t)(n0 + nl2) * MM))[mc];
  }
  // stage W tile [64b x 64n] (pad 66)
#pragma unroll
  for (int rep = 0; rep < 16; rep++) {
    const int idx = rep * 256 + t;
    const int b = idx >> 6, nl = idx & 63;
    w_sh[b * 66 + nl] = W[(size_t)b * NN + n0 + nl];
  }
  __syncthreads();
  const int mq = t & 15, bq = t >> 4;
  float4 acc[4];
#pragma unroll
  for (int j = 0; j < 4; j++) acc[j] = make_float4(0.f, 0.f, 0.f, 0.f);
#pragma unroll 4
  for (int nn = 0; nn < 64; nn++) {
    const float4 mv = *((const float4*)&m1_sh[nn * 68 + mq * 4]);
    const float w0 = w_sh[(bq * 4 + 0) * 66 + nn];
    const float w1 = w_sh[(bq * 4 + 1) * 66 + nn];
    const float w2 = w_sh[(bq * 4 + 2) * 66 + nn];
    const float w3 = w_sh[(bq * 4 + 3) * 66 + nn];
    acc[0].x += w0 * mv.x; acc[0].y += w0 * mv.y; acc[0].z += w0 * mv.z; acc[0].w += w0 * mv.w;
    acc[1].x += w1 * mv.x; acc[1].y += w1 * mv.y; acc[1].z += w1 * mv.z; acc[1].w += w1 * mv.w;
    acc[2].x += w2 * mv.x; acc[2].y += w2 * mv.y; acc[2].z += w2 * mv.z; acc[2].w += w2 * mv.w;
    acc[3].x += w3 * mv.x; acc[3].y += w3 * mv.y; acc[3].z += w3 * mv.z; acc[3].w += w3 * mv.w;
  }
  float* pp = part + (size_t)sc * 4096;
#pragma unroll
  for (int j = 0; j < 4; j++)
    *((float4*)&pp[(bq * 4 + j) * 64 + mq * 4]) = acc[j];
}

// ---------------------------------------------------------------------------
// K6b (per r): reduce 1024 part slabs into acc_out[r] (zeroed by prep).
// grid (16, 8), block 256: each block sums 128 slabs, one atomicAdd/elem.
// ---------------------------------------------------------------------------
__global__ __launch_bounds__(256) void reduce_part_kernel(
    const float* __restrict__ part, float* __restrict__ accout)
{
  const int off = blockIdx.x * 256 + threadIdx.x;  // 0..4095
  const int s0 = blockIdx.y * 128;
  float sum = 0.f;
#pragma unroll 8
  for (int k = 0; k < 128; k++) sum += part[(size_t)(s0 + k) * 4096 + off];
  atomicAdd(&accout[off], sum);
}

// ---------------------------------------------------------------------------
// K7: normalize by GS_r and write out[b][r*64+m]. grid 64, block 256.
// ---------------------------------------------------------------------------
__global__ __launch_bounds__(256) void normalize_kernel(
    const float* __restrict__ accout, const float* __restrict__ GS,
    float* __restrict__ out)
{
  const int idx = blockIdx.x * 256 + threadIdx.x;  // 0..16383
  const int rm = idx & 255, r = rm >> 6, m = rm & 63;
  const int b = idx >> 8;
  out[idx] = accout[r * 4096 + b * 64 + m] / (GS[1 + r] + 1e-5f);
}

// ---------------------------------------------------------------------------
extern "C" void kernel_launch(void* const* d_in, const int* in_sizes, int n_in,
                              void* d_out, int out_size, void* d_ws, size_t ws_size,
                              hipStream_t stream) {
  (void)in_sizes; (void)n_in; (void)out_size; (void)ws_size;
  const float* h_t    = (const float*)d_in[0];
  const float* ww     = (const float*)d_in[1];
  const float* wr     = (const float*)d_in[2];
  const float* memory = (const float*)d_in[3];
  const float* key_w  = (const float*)d_in[4];
  const float* key_b  = (const float*)d_in[5];
  const float* beta_w = (const float*)d_in[6];
  const float* beta_b = (const float*)d_in[7];
  const float* gate_w = (const float*)d_in[8];
  const float* gate_b = (const float*)d_in[9];
  const float* shift_w = (const float*)d_in[10];
  const float* shift_b = (const float*)d_in[11];
  const float* gamma_w = (const float*)d_in[12];
  const float* gamma_b = (const float*)d_in[13];
  const float* erase_w = (const float*)d_in[14];
  const float* erase_b = (const float*)d_in[15];
  const float* add_w   = (const float*)d_in[16];
  const float* add_b   = (const float*)d_in[17];
  const int*   bank    = (const int*)d_in[18];

  float* ws = (float*)d_ws;
  // Layout (floats), 4 x 16MB slabs + small:
  //   A [0,       4194304): E0 (content0->wpow0), then part (gemm_r->reduce_r)
  //   B [4194304, 8388608): W0 (wpow0->apply), then W_r per read head
  //   C [8388608, 12582912): m1 (live apply -> last gemm)
  //   D [12582912,16777216): E1 (content1 -> last wpow)
  float* E0   = ws;
  float* part = ws;
  float* W    = ws + 4194304;
  float* m1   = ws + 8388608;
  float* E1   = ws + 12582912;
  float* smallb  = ws + 16777216;
  float* acc_out = smallb;             // 16384 (4 r x 64 b x 64 m)
  float* kn    = smallb + 16384;       // 4096
  float* e_v   = smallb + 20480;       // 4096
  float* a_v   = smallb + 24576;       // 4096
  float* beta  = smallb + 28672;       // 64
  float* g     = smallb + 28736;       // 64
  float* gam   = smallb + 28800;       // 64
  float* s     = smallb + 28864;       // 192
  float* RS0   = smallb + 29056;       // 64
  float* RS1   = smallb + 29120;       // 64
  float* GS    = smallb + 29184;       // 5: [0]=GS0, [1..4]=GS_r

  prep_kernel<<<64, 256, 0, stream>>>(h_t, key_w, key_b, beta_w, beta_b,
                                      gate_w, gate_b, shift_w, shift_b,
                                      gamma_w, gamma_b, erase_w, erase_b,
                                      add_w, add_b,
                                      kn, e_v, a_v, beta, g, gam, s,
                                      RS0, RS1, GS, acc_out);
  content_kernel<<<dim3(512, 2), 256, 0, stream>>>(memory, bank, kn, beta, E0, RS0);
  wpow_kernel<<<dim3(64, 64), 256, 0, stream>>>(E0, ww, RS0, g, gam, s, W, &GS[0]);
  apply_write_kernel<<<1024, 256, 0, stream>>>(W, GS, e_v, a_v, memory, bank, m1);
  content_kernel<<<dim3(512, 2), 256, 0, stream>>>(m1, nullptr, kn, beta, E1, RS1);
  for (int r = 0; r < 4; r++) {
    wpow_kernel<<<dim3(64, 64), 256, 0, stream>>>(
        E1, wr + (size_t)r * BB * NN, RS1, g, gam, s, W, GS + 1 + r);
    gemm_kernel<<<1024, 256, 0, stream>>>(W, m1, part);
    reduce_part_kernel<<<dim3(16, 8), 256, 0, stream>>>(part, acc_out + r * 4096);
  }
  normalize_kernel<<<64, 256, 0, stream>>>(acc_out, GS, (float*)d_out);
}

// Round 7
// 434.647 us; speedup vs baseline: 1.5866x; 1.5866x over previous
//
#include <hip/hip_runtime.h>

#define NN 65536
#define BB 64
#define HH 1024
#define MM 64
#define RR 4

__device__ __forceinline__ float waveReduceSum(float v) {
#pragma unroll
  for (int off = 32; off > 0; off >>= 1) v += __shfl_xor(v, off, 64);
  return v;
}

__device__ __forceinline__ float fastPow(float wt, float p) {
  return __expf(p * __logf(wt));
}

// shifted, gated interpolation weight at n (lane == n % 64).
__device__ __forceinline__ float shifted_wg(
    const float* __restrict__ Eb, const float* __restrict__ wb, int n,
    float gb, float rinv, float s0, float s1, float s2) {
  const int lane = threadIdx.x & 63;
  const float omg = 1.f - gb;
  const float wgc = gb * Eb[n] * rinv + omg * wb[n];
  float wgm = __shfl_up(wgc, 1, 64);
  float wgp = __shfl_down(wgc, 1, 64);
  if (lane == 0)  wgm = (n > 0)      ? (gb * Eb[n - 1] * rinv + omg * wb[n - 1]) : 0.f;
  if (lane == 63) wgp = (n < NN - 1) ? (gb * Eb[n + 1] * rinv + omg * wb[n + 1]) : 0.f;
  return s0 * wgm + s1 * wgc + s2 * wgp;
}

// ---------------------------------------------------------------------------
// K1a: partial dots for the three 1024x64 GEMMs. grid (12, 64), block 256.
// bx = mat*4 + hchunk. Thread (c = t&63, q = t>>6) covers 64 h values.
// Also zero-inits RSp / GSp (selected blocks).
// ---------------------------------------------------------------------------
__global__ __launch_bounds__(256) void prep1_kernel(
    const float* __restrict__ h_t,
    const float* __restrict__ key_w, const float* __restrict__ erase_w,
    const float* __restrict__ add_w,
    float* __restrict__ prep_part,
    float* __restrict__ RS0p, float* __restrict__ RS1p, float* __restrict__ GSp)
{
  const int b = blockIdx.y;
  const int mat = blockIdx.x >> 2, chunk = blockIdx.x & 3;
  const int t = threadIdx.x;
  // zero-init small accumulators
  if (mat == 0 && chunk == 0) { RS0p[b * 256 + t] = 0.f; RS1p[b * 256 + t] = 0.f; }
  if (mat == 0 && chunk == 1 && b < 20) GSp[b * 256 + t] = 0.f;

  const float* Wm = (mat == 0) ? key_w : ((mat == 1) ? erase_w : add_w);
  const int c = t & 63, q = t >> 6;
  const int h0 = chunk * 256 + q * 64;
  float d = 0.f;
#pragma unroll 8
  for (int i = 0; i < 64; i++)
    d += h_t[b * HH + h0 + i] * Wm[(h0 + i) * 64 + c];
  __shared__ float red[64][5];
  red[c][q] = d;
  __syncthreads();
  if (t < 64)
    prep_part[((b * 3 + mat) * 4 + chunk) * 64 + t] =
        red[t][0] + red[t][1] + red[t][2] + red[t][3];
}

// ---------------------------------------------------------------------------
// K1b: reduce partials + activations + small dots + kn. grid 64, block 256.
// ---------------------------------------------------------------------------
__global__ __launch_bounds__(256) void prep2_kernel(
    const float* __restrict__ h_t, const float* __restrict__ prep_part,
    const float* __restrict__ key_b,
    const float* __restrict__ beta_w, const float* __restrict__ beta_b,
    const float* __restrict__ gate_w, const float* __restrict__ gate_b,
    const float* __restrict__ shift_w, const float* __restrict__ shift_b,
    const float* __restrict__ gamma_w, const float* __restrict__ gamma_b,
    const float* __restrict__ erase_b, const float* __restrict__ add_b,
    float* __restrict__ kn, float* __restrict__ e_v, float* __restrict__ a_v,
    float* __restrict__ g, float* __restrict__ gamma_,
    float* __restrict__ s, float* __restrict__ betaGlob)
{
  const int b = blockIdx.x;
  const int t = threadIdx.x;
  __shared__ float k_sh[64];
  if (t < 192) {
    const int mat = t >> 6, c = t & 63;
    const float* pp = prep_part + ((b * 3 + mat) * 4) * 64 + c;
    const float v = pp[0] + pp[64] + pp[128] + pp[192];
    if (mat == 0) k_sh[c] = fminf(fmaxf(v + key_b[c], 0.f), 1.f);
    else if (mat == 1) e_v[b * 64 + c] = fminf(fmaxf(v + erase_b[c], 0.f), 1.f);
    else a_v[b * 64 + c] = fminf(fmaxf(v + add_b[c], 0.f), 1.f);
  } else {
    const int lane = t - 192;
    float o0 = 0.f, o1 = 0.f, o2 = 0.f, o3 = 0.f, o4 = 0.f, o5 = 0.f;
#pragma unroll 4
    for (int k = 0; k < 16; k++) {
      const int hh = lane + k * 64;
      const float hv = h_t[b * HH + hh];
      o0 += hv * beta_w[hh];
      o1 += hv * gate_w[hh];
      o2 += hv * gamma_w[hh];
      o3 += hv * shift_w[hh * 3 + 0];
      o4 += hv * shift_w[hh * 3 + 1];
      o5 += hv * shift_w[hh * 3 + 2];
    }
    o0 = waveReduceSum(o0); o1 = waveReduceSum(o1); o2 = waveReduceSum(o2);
    o3 = waveReduceSum(o3); o4 = waveReduceSum(o4); o5 = waveReduceSum(o5);
    if (lane == 0) {
      betaGlob[b] = fmaxf(o0 + beta_b[0], 0.f);
      g[b]        = fminf(fmaxf(o1 + gate_b[0], 0.f), 1.f);
      gamma_[b]   = 1.0f + fmaxf(o2 + gamma_b[0], 0.f);
      const float l0 = o3 + shift_b[0], l1 = o4 + shift_b[1], l2 = o5 + shift_b[2];
      const float mx = fmaxf(l0, fmaxf(l1, l2));
      const float e0 = __expf(l0 - mx), e1 = __expf(l1 - mx), e2 = __expf(l2 - mx);
      const float inv = 1.f / (e0 + e1 + e2);
      s[b * 3 + 0] = e0 * inv; s[b * 3 + 1] = e1 * inv; s[b * 3 + 2] = e2 * inv;
    }
  }
  __syncthreads();
  if (t < 64) {
    float ss = 0.f;
    for (int j = 0; j < 64; j++) ss += k_sh[j] * k_sh[j];
    kn[b * 64 + t] = k_sh[t] / (sqrtf(ss) + 1e-8f);
  }
}

// ---------------------------------------------------------------------------
// K2 / K5: content addressing. grid (512 n-chunks of 128, 2 b-halves), 256 t.
// RS partials go to RSp[b*256 + slot*16], slot = blockIdx.x & 15 (32-way).
// ---------------------------------------------------------------------------
__global__ __launch_bounds__(256) void content_kernel(
    const float* __restrict__ mem, const int* __restrict__ bank,
    const float* __restrict__ kn, const float* __restrict__ beta,
    float* __restrict__ E, float* __restrict__ RSp)
{
  const float* Mrow = mem + (bank ? ((size_t)(*bank) * (size_t)NN * MM) : (size_t)0);
  const int t = threadIdx.x;
  const int nl = t & 127;
  const int n = blockIdx.x * 128 + nl;
  const int bgrp = t >> 7;
  const int nhalf = (t >> 6) & 1;
  const int lane = t & 63;
  const int b0 = blockIdx.y * 32 + bgrp * 16;

  float4 row[16];
  const float4* rp = (const float4*)(Mrow + (size_t)n * MM);
#pragma unroll
  for (int q = 0; q < 16; q++) row[q] = rp[q];
  float ss = 0.f;
#pragma unroll
  for (int q = 0; q < 16; q++)
    ss += row[q].x * row[q].x + row[q].y * row[q].y + row[q].z * row[q].z + row[q].w * row[q].w;
  const float rinv = 1.0f / (sqrtf(ss) + 1e-8f);

  __shared__ float accs[32][2];
  for (int i = 0; i < 16; i++) {
    const int rb = __builtin_amdgcn_readfirstlane(b0 + i);
    const float4* kp = (const float4*)(kn + rb * 64);
    float dot = 0.f;
#pragma unroll
    for (int q = 0; q < 16; q++) {
      const float4 kq = kp[q];
      dot += kq.x * row[q].x + kq.y * row[q].y + kq.z * row[q].z + kq.w * row[q].w;
    }
    const float e = __expf(beta[rb] * dot * rinv);
    E[(size_t)rb * NN + n] = e;
    const float r = waveReduceSum(e);
    if (lane == 0) accs[bgrp * 16 + i][nhalf] = r;
  }
  __syncthreads();
  if (t < 32)
    atomicAdd(&RSp[(blockIdx.y * 32 + t) * 256 + (blockIdx.x & 15) * 16],
              accs[t][0] + accs[t][1]);
}

// ---------------------------------------------------------------------------
// K3: streaming w_pow producer. grid (64 n-chunks of 1024, 64 b), block 256.
// GS partial -> GSp[slot*1024 + b*16] (64-way contention, 64B-padded).
// ---------------------------------------------------------------------------
__global__ __launch_bounds__(256) void wpow_kernel(
    const float* __restrict__ E, const float* __restrict__ wprev,
    const float* __restrict__ RSp, const float* __restrict__ g,
    const float* __restrict__ gamma_, const float* __restrict__ s,
    float* __restrict__ W, float* __restrict__ GSp, int slot)
{
  const int b = blockIdx.y;
  const float gb = g[b], gmb = gamma_[b];
  const float s0 = s[b * 3], s1 = s[b * 3 + 1], s2 = s[b * 3 + 2];
  float rs = 0.f;
#pragma unroll
  for (int j = 0; j < 16; j++) rs += RSp[b * 256 + j * 16];
  const float rinv = 1.0f / rs;
  const float* Eb = E + (size_t)b * NN;
  const float* wb = wprev + (size_t)b * NN;
  float* Wb = W + (size_t)b * NN;
  const int base = blockIdx.x * 1024;
  float acc = 0.f;
#pragma unroll
  for (int k = 0; k < 4; k++) {
    const int n = base + k * 256 + threadIdx.x;
    const float wt = shifted_wg(Eb, wb, n, gb, rinv, s0, s1, s2);
    const float wp = fastPow(wt, gmb);
    Wb[n] = wp;
    acc += wp;
  }
  __shared__ float wsum[4];
  const float w = waveReduceSum(acc);
  if ((threadIdx.x & 63) == 0) wsum[threadIdx.x >> 6] = w;
  __syncthreads();
  if (threadIdx.x == 0)
    atomicAdd(&GSp[slot * 1024 + b * 16], wsum[0] + wsum[1] + wsum[2] + wsum[3]);
}

// ---------------------------------------------------------------------------
// K4: apply write head. grid 1024 (64-n), block 256. cw staged from W0*invGS.
// ---------------------------------------------------------------------------
__global__ __launch_bounds__(256) void apply_write_kernel(
    const float* __restrict__ W0, const float* __restrict__ GSp,
    const float* __restrict__ e_v, const float* __restrict__ a_v,
    const float* __restrict__ memory, const int* __restrict__ bank,
    float* __restrict__ m1)
{
  __shared__ float cw[64 * 68];
  __shared__ float e_sh[4096];
  __shared__ float a_sh[4096];
  const int t = threadIdx.x;
  const int n0 = blockIdx.x * 64;
  float gs = 0.f;
#pragma unroll
  for (int j = 0; j < 64; j++) gs += GSp[j * 16];
  const float invGS = 1.0f / (gs + 1e-5f);
#pragma unroll
  for (int q = 0; q < 4; q++) {
    ((float4*)e_sh)[t + 256 * q] = ((const float4*)e_v)[t + 256 * q];
    ((float4*)a_sh)[t + 256 * q] = ((const float4*)a_v)[t + 256 * q];
  }
#pragma unroll
  for (int rep = 0; rep < 4; rep++) {
    const int idx = rep * 256 + t;
    const int b = idx >> 4, nc = idx & 15;
    float4 v = *((const float4*)(W0 + (size_t)b * NN + n0 + nc * 4));
    v.x *= invGS; v.y *= invGS; v.z *= invGS; v.w *= invGS;
    *((float4*)&cw[b * 68 + nc * 4]) = v;
  }
  __syncthreads();
  const int nl = t >> 2, mq = t & 3;
  const int n = n0 + nl;
  float er[16], ad[16];
#pragma unroll
  for (int j = 0; j < 16; j++) { er[j] = 0.f; ad[j] = 0.f; }
  for (int b = 0; b < 64; b++) {
    const float c = cw[b * 68 + nl];
#pragma unroll
    for (int j = 0; j < 4; j++) {
      const float4 ev = *((const float4*)&e_sh[b * 64 + mq * 16 + j * 4]);
      const float4 av = *((const float4*)&a_sh[b * 64 + mq * 16 + j * 4]);
      er[j * 4 + 0] += c * ev.x; er[j * 4 + 1] += c * ev.y;
      er[j * 4 + 2] += c * ev.z; er[j * 4 + 3] += c * ev.w;
      ad[j * 4 + 0] += c * av.x; ad[j * 4 + 1] += c * av.y;
      ad[j * 4 + 2] += c * av.z; ad[j * 4 + 3] += c * av.w;
    }
  }
  const float* M0 = memory + (size_t)(*bank) * (size_t)NN * MM;
  const float4* m0p = (const float4*)(M0 + (size_t)n * MM + mq * 16);
  float4* m1p = (float4*)(m1 + (size_t)n * MM + mq * 16);
#pragma unroll
  for (int j = 0; j < 4; j++) {
    const float4 mv = m0p[j];
    float4 o;
    o.x = mv.x * (1.f - er[j * 4 + 0]) + ad[j * 4 + 0];
    o.y = mv.y * (1.f - er[j * 4 + 1]) + ad[j * 4 + 1];
    o.z = mv.z * (1.f - er[j * 4 + 2]) + ad[j * 4 + 2];
    o.w = mv.w * (1.f - er[j * 4 + 3]) + ad[j * 4 + 3];
    m1p[j] = o;
  }
}

// ---------------------------------------------------------------------------
// K6 (per r): part[sc][b][m] = sum_{n in sc} W[b][n] * m1[n][m]. grid 1024.
// ---------------------------------------------------------------------------
__global__ __launch_bounds__(256) void gemm_kernel(
    const float* __restrict__ W, const float* __restrict__ m1,
    float* __restrict__ part)
{
  const int sc = blockIdx.x;
  const int t = threadIdx.x;
  const int n0 = sc * 64;
  __shared__ float m1_sh[64 * 68];
  __shared__ float w_sh[64 * 68];
#pragma unroll
  for (int rep = 0; rep < 4; rep++) {
    const int nl2 = rep * 16 + (t >> 4);
    const int mc = t & 15;
    *((float4*)&m1_sh[nl2 * 68 + mc * 4]) =
        ((const float4*)(m1 + (size_t)(n0 + nl2) * MM))[mc];
  }
#pragma unroll
  for (int rep = 0; rep < 4; rep++) {
    const int idx = rep * 256 + t;
    const int b = idx >> 4, nc = idx & 15;
    *((float4*)&w_sh[b * 68 + nc * 4]) =
        *((const float4*)(W + (size_t)b * NN + n0 + nc * 4));
  }
  __syncthreads();
  const int mq = t & 15, bq = t >> 4;
  float4 acc[4];
#pragma unroll
  for (int j = 0; j < 4; j++) acc[j] = make_float4(0.f, 0.f, 0.f, 0.f);
#pragma unroll 4
  for (int nn = 0; nn < 64; nn++) {
    const float4 mv = *((const float4*)&m1_sh[nn * 68 + mq * 4]);
    const float w0 = w_sh[(bq * 4 + 0) * 68 + nn];
    const float w1 = w_sh[(bq * 4 + 1) * 68 + nn];
    const float w2 = w_sh[(bq * 4 + 2) * 68 + nn];
    const float w3 = w_sh[(bq * 4 + 3) * 68 + nn];
    acc[0].x += w0 * mv.x; acc[0].y += w0 * mv.y; acc[0].z += w0 * mv.z; acc[0].w += w0 * mv.w;
    acc[1].x += w1 * mv.x; acc[1].y += w1 * mv.y; acc[1].z += w1 * mv.z; acc[1].w += w1 * mv.w;
    acc[2].x += w2 * mv.x; acc[2].y += w2 * mv.y; acc[2].z += w2 * mv.z; acc[2].w += w2 * mv.w;
    acc[3].x += w3 * mv.x; acc[3].y += w3 * mv.y; acc[3].z += w3 * mv.z; acc[3].w += w3 * mv.w;
  }
  float* pp = part + (size_t)sc * 4096;
#pragma unroll
  for (int j = 0; j < 4; j++)
    *((float4*)&pp[(bq * 4 + j) * 64 + mq * 4]) = acc[j];
}

// ---------------------------------------------------------------------------
// K6b: reduce 1024 slabs -> 64 slabs (no atomics). grid (16, 64), block 256.
// ---------------------------------------------------------------------------
__global__ __launch_bounds__(256) void reduce1_kernel(
    const float* __restrict__ part, float* __restrict__ part2)
{
  const int off = blockIdx.x * 256 + threadIdx.x;  // 0..4095
  const int s0 = blockIdx.y * 16;
  float sum = 0.f;
#pragma unroll
  for (int k = 0; k < 16; k++) sum += part[(size_t)(s0 + k) * 4096 + off];
  part2[(size_t)blockIdx.y * 4096 + off] = sum;
}

// ---------------------------------------------------------------------------
// K6c: reduce 64 slabs -> acc_out[r]. grid 16, block 256.
// ---------------------------------------------------------------------------
__global__ __launch_bounds__(256) void reduce2_kernel(
    const float* __restrict__ part2, float* __restrict__ accout)
{
  const int off = blockIdx.x * 256 + threadIdx.x;  // 0..4095
  float sum = 0.f;
#pragma unroll 8
  for (int k = 0; k < 64; k++) sum += part2[(size_t)k * 4096 + off];
  accout[off] = sum;
}

// ---------------------------------------------------------------------------
// K7: normalize by GS_r (summed from GSp) and write out. grid 64, block 256.
// ---------------------------------------------------------------------------
__global__ __launch_bounds__(256) void normalize_kernel(
    const float* __restrict__ accout, const float* __restrict__ GSp,
    float* __restrict__ out)
{
  __shared__ float gs_sh[4];
  const int t = threadIdx.x;
  const int wv = t >> 6, ln = t & 63;
  float v = GSp[(1 + wv) * 1024 + ln * 16];
  v = waveReduceSum(v);
  if (ln == 0) gs_sh[wv] = v;
  __syncthreads();
  const int idx = blockIdx.x * 256 + t;  // 0..16383
  const int b = idx >> 8, rm = idx & 255, r = rm >> 6, m = rm & 63;
  out[idx] = accout[r * 4096 + b * 64 + m] / (gs_sh[r] + 1e-5f);
}

// ---------------------------------------------------------------------------
extern "C" void kernel_launch(void* const* d_in, const int* in_sizes, int n_in,
                              void* d_out, int out_size, void* d_ws, size_t ws_size,
                              hipStream_t stream) {
  (void)in_sizes; (void)n_in; (void)out_size; (void)ws_size;
  const float* h_t    = (const float*)d_in[0];
  const float* ww     = (const float*)d_in[1];
  const float* wr     = (const float*)d_in[2];
  const float* memory = (const float*)d_in[3];
  const float* key_w  = (const float*)d_in[4];
  const float* key_b  = (const float*)d_in[5];
  const float* beta_w = (const float*)d_in[6];
  const float* beta_b = (const float*)d_in[7];
  const float* gate_w = (const float*)d_in[8];
  const float* gate_b = (const float*)d_in[9];
  const float* shift_w = (const float*)d_in[10];
  const float* shift_b = (const float*)d_in[11];
  const float* gamma_w = (const float*)d_in[12];
  const float* gamma_b = (const float*)d_in[13];
  const float* erase_w = (const float*)d_in[14];
  const float* erase_b = (const float*)d_in[15];
  const float* add_w   = (const float*)d_in[16];
  const float* add_b   = (const float*)d_in[17];
  const int*   bank    = (const int*)d_in[18];

  float* ws = (float*)d_ws;
  // 4 x 16MB slabs:
  //   A: E0 (content0->wpow0), then part (gemm_r -> reduce1_r)
  //   B: W0 (wpow0->apply), then W_r (wpow_r->gemm_r), then part2 (reduce1->reduce2)
  //   C: m1 (apply -> last gemm)
  //   D: E1 (content1 -> last wpow)
  float* E0    = ws;
  float* part  = ws;
  float* W     = ws + 4194304;
  float* part2 = ws + 4194304;
  float* m1    = ws + 8388608;
  float* E1    = ws + 12582912;
  float* smallb  = ws + 16777216;
  float* acc_out  = smallb;              // 16384
  float* kn       = smallb + 16384;      // 4096
  float* e_v      = smallb + 20480;      // 4096
  float* a_v      = smallb + 24576;      // 4096
  float* betaB    = smallb + 28672;      // 64
  float* g        = smallb + 28736;      // 64
  float* gam      = smallb + 28800;      // 64
  float* s        = smallb + 28864;      // 256 (192 used)
  float* RS0p     = smallb + 29120;      // 16384 (64 b x 16 slots x 16 pad)
  float* RS1p     = smallb + 45504;      // 16384
  float* GSp      = smallb + 61888;      // 5120 (5 slots x 64 b x 16 pad)
  float* prep_part = smallb + 67008;     // 49152

  prep1_kernel<<<dim3(12, 64), 256, 0, stream>>>(h_t, key_w, erase_w, add_w,
                                                 prep_part, RS0p, RS1p, GSp);
  prep2_kernel<<<64, 256, 0, stream>>>(h_t, prep_part, key_b,
                                       beta_w, beta_b, gate_w, gate_b,
                                       shift_w, shift_b, gamma_w, gamma_b,
                                       erase_b, add_b,
                                       kn, e_v, a_v, g, gam, s, betaB);
  content_kernel<<<dim3(512, 2), 256, 0, stream>>>(memory, bank, kn, betaB, E0, RS0p);
  wpow_kernel<<<dim3(64, 64), 256, 0, stream>>>(E0, ww, RS0p, g, gam, s, W, GSp, 0);
  apply_write_kernel<<<1024, 256, 0, stream>>>(W, GSp, e_v, a_v, memory, bank, m1);
  content_kernel<<<dim3(512, 2), 256, 0, stream>>>(m1, nullptr, kn, betaB, E1, RS1p);
  for (int r = 0; r < 4; r++) {
    wpow_kernel<<<dim3(64, 64), 256, 0, stream>>>(
        E1, wr + (size_t)r * BB * NN, RS1p, g, gam, s, W, GSp, 1 + r);
    gemm_kernel<<<1024, 256, 0, stream>>>(W, m1, part);
    reduce1_kernel<<<dim3(16, 64), 256, 0, stream>>>(part, part2);
    reduce2_kernel<<<16, 256, 0, stream>>>(part2, acc_out + r * 4096);
  }
  normalize_kernel<<<64, 256, 0, stream>>>(acc_out, GSp, (float*)d_out);
}